// Round 1
// baseline (1992.276 us; speedup 1.0000x reference)
//
#include <hip/hip_runtime.h>
#include <math.h>

// Needs ws_size >= 249,803,264 bytes.

#define NPT   25000
#define NN    100000
#define EE    600000
#define HD    128
#define NRELS 8

typedef unsigned short u16;
typedef unsigned int   u32;
using s16x8 = __attribute__((ext_vector_type(8))) short;
using f32x4 = __attribute__((ext_vector_type(4))) float;

__device__ __forceinline__ u16 f2bf(float x){
  u32 u = __float_as_uint(x);
  u += 0x7fffu + ((u >> 16) & 1u);
  return (u16)(u >> 16);
}
__device__ __forceinline__ u32 encf(float f){
  u32 u = __float_as_uint(f);
  return (u & 0x80000000u) ? ~u : (u | 0x80000000u);
}
__device__ __forceinline__ float decf(u32 u){
  return __uint_as_float((u & 0x80000000u) ? (u ^ 0x80000000u) : ~u);
}

// ---------- weight cast+transpose: in [K][N] f32 -> out [N][K] bf16, batched on blockIdx.y
__global__ __launch_bounds__(256) void cast_tr(const float* __restrict__ in,
                                               u16* __restrict__ out, int K, int N){
  long b = blockIdx.y;
  const float* ib = in + b * (long)K * N;
  u16* ob = out + b * (long)K * N;
  int idx = blockIdx.x * 256 + threadIdx.x;
  if (idx < K * N){
    int n = idx / K, k = idx - n * K;   // K is a power of two here
    ob[idx] = f2bf(ib[(long)k * N + n]);
  }
}

// ---------- relation-bucket counting sort (meta: [0..8)=hist, [8..16)=cursor, [16..25)=offsets)
__global__ __launch_bounds__(256) void hist_k(const int* __restrict__ et, int* meta){
  __shared__ int lh[NRELS];
  if (threadIdx.x < NRELS) lh[threadIdx.x] = 0;
  __syncthreads();
  int e = blockIdx.x * 256 + threadIdx.x;
  if (e < EE) atomicAdd(&lh[et[e]], 1);
  __syncthreads();
  if (threadIdx.x < NRELS && lh[threadIdx.x] > 0) atomicAdd(&meta[threadIdx.x], lh[threadIdx.x]);
}

__global__ void scan_k(int* meta){
  if (threadIdx.x == 0 && blockIdx.x == 0){
    int off = 0;
    for (int r = 0; r < NRELS; r++){ meta[16 + r] = off; meta[8 + r] = off; off += meta[r]; }
    meta[24] = off;  // == EE
  }
}

__global__ __launch_bounds__(256) void scatter_k(const int* __restrict__ ei,
                                                 const int* __restrict__ et, int* meta,
                                                 int* __restrict__ ss, int* __restrict__ sd){
  __shared__ int lcount[NRELS], lbase[NRELS];
  if (threadIdx.x < NRELS) lcount[threadIdx.x] = 0;
  __syncthreads();
  int e = blockIdx.x * 256 + threadIdx.x;
  int r = 0, myrank = 0;
  if (e < EE){ r = et[e]; myrank = atomicAdd(&lcount[r], 1); }
  __syncthreads();
  if (threadIdx.x < NRELS && lcount[threadIdx.x] > 0)
    lbase[threadIdx.x] = atomicAdd(&meta[8 + threadIdx.x], lcount[threadIdx.x]);
  __syncthreads();
  if (e < EE){
    int p = lbase[r] + myrank;
    ss[p] = ei[e];
    sd[p] = ei[EE + e];
  }
}

// ---------- bf16 MFMA GEMM: C[M][N] = act(A[M][K] @ Bt[N][K]^T + bias)
// APRO: 0 = A is bf16; 1 = A is f32 (cast while staging); 2 = A is f32 res, apply gelu(x/max(den,1e-9))
template<int APRO, bool RELU, bool OUTF32, bool OUTBF16>
__global__ __launch_bounds__(256)
void gemm_k(const void* __restrict__ Ap, const u16* __restrict__ Bt,
            const float* __restrict__ bias, const float* __restrict__ den,
            float* __restrict__ Cf, u16* __restrict__ Cbf,
            int M, int N, int K, int sAr, int sB, int sBias, int sCr)
{
  __shared__ __align__(16) u16 As[128 * 40];
  __shared__ __align__(16) u16 Bs[128 * 40];
  int z = blockIdx.z;
  int tid = threadIdx.x, wv = tid >> 6, lane = tid & 63;
  int m0 = blockIdx.x * 128, n0 = blockIdx.y * 128;
  int wm = (wv >> 1) * 64, wn = (wv & 1) * 64;
  long aBase = (long)z * sAr * K;
  const u16*   Ab  = (const u16*)Ap;
  const float* Afp = (const float*)Ap;
  const u16* Bz = Bt + (long)z * sB;
  const float* biz = bias + (long)z * sBias;
  long cRow0 = (long)z * sCr;
  int r2 = tid >> 1, hf = tid & 1;

  f32x4 acc[4][4];
  #pragma unroll
  for (int i = 0; i < 4; i++)
    #pragma unroll
    for (int j = 0; j < 4; j++) acc[i][j] = (f32x4){0.f, 0.f, 0.f, 0.f};

  for (int kk = 0; kk < K; kk += 32){
    // stage A (128 x 32)
    {
      int gm = m0 + r2;
      #pragma unroll
      for (int c = 0; c < 2; c++){
        int ko = kk + c * 16 + hf * 8;
        union { u16 us[8]; uint4 v; } pk;
        if (gm < M){
          if (APRO == 0){
            pk.v = *(const uint4*)(Ab + aBase + (long)gm * K + ko);
          } else {
            const float* s = Afp + aBase + (long)gm * K + ko;
            float4 f0 = *(const float4*)s;
            float4 f1 = *(const float4*)(s + 4);
            float fv[8] = {f0.x, f0.y, f0.z, f0.w, f1.x, f1.y, f1.z, f1.w};
            #pragma unroll
            for (int j = 0; j < 8; j++){
              float x = fv[j];
              if (APRO == 2){
                long nodeg = (long)z * sAr + gm;
                int head = (ko + j) >> 5;
                float dd = den[nodeg * 4 + head];
                x = x / fmaxf(dd, 1e-9f);
                x = 0.5f * x * (1.0f + erff(x * 0.70710678118654752f));
              }
              pk.us[j] = f2bf(x);
            }
          }
        } else {
          pk.v = make_uint4(0u, 0u, 0u, 0u);
        }
        *(uint4*)&As[r2 * 40 + c * 16 + hf * 8] = pk.v;
      }
    }
    // stage B (128 x 32 from Bt[N][K])
    {
      int gn = n0 + r2;
      #pragma unroll
      for (int c = 0; c < 2; c++){
        int ko = kk + c * 16 + hf * 8;
        uint4 v;
        if (gn < N) v = *(const uint4*)(Bz + (long)gn * K + ko);
        else        v = make_uint4(0u, 0u, 0u, 0u);
        *(uint4*)&Bs[r2 * 40 + c * 16 + hf * 8] = v;
      }
    }
    __syncthreads();
    s16x8 af[4], bfr[4];
    int rr = lane & 15, q8 = (lane >> 4) * 8;
    #pragma unroll
    for (int mt = 0; mt < 4; mt++) af[mt]  = *(const s16x8*)&As[(wm + mt * 16 + rr) * 40 + q8];
    #pragma unroll
    for (int nt = 0; nt < 4; nt++) bfr[nt] = *(const s16x8*)&Bs[(wn + nt * 16 + rr) * 40 + q8];
    #pragma unroll
    for (int mt = 0; mt < 4; mt++)
      #pragma unroll
      for (int nt = 0; nt < 4; nt++)
        acc[mt][nt] = __builtin_amdgcn_mfma_f32_16x16x32_bf16(af[mt], bfr[nt], acc[mt][nt], 0, 0, 0);
    __syncthreads();
  }
  // epilogue: C/D layout col=lane&15, row=(lane>>4)*4+r
  int col = lane & 15, row4 = (lane >> 4) * 4;
  #pragma unroll
  for (int mt = 0; mt < 4; mt++){
    #pragma unroll
    for (int nt = 0; nt < 4; nt++){
      int gn = n0 + wn + nt * 16 + col;
      float bb = (gn < N) ? biz[gn] : 0.f;
      #pragma unroll
      for (int r = 0; r < 4; r++){
        int gm = m0 + wm + mt * 16 + row4 + r;
        if (gm < M && gn < N){
          float vv = acc[mt][nt][r] + bb;
          if (RELU) vv = fmaxf(vv, 0.f);
          long ci = (cRow0 + gm) * (long)N + gn;
          if (OUTF32)  Cf[ci]  = vv;
          if (OUTBF16) Cbf[ci] = f2bf(vv);
        }
      }
    }
  }
}

// ---------- edge pass A: att[e,h] = (q_d . (ra[r,h] k_s)) * rp * 1/sqrt(32); atomicMax amax
// blocks: (x covers edges/128, y = relation). Each wave: 32 edges. Relation matrix in registers:
// lane (hp,f) holds ra[h][*][f] for h=hp and h=hp+2.
__global__ __launch_bounds__(256)
void edge_att(const float* __restrict__ kv, const float* __restrict__ qv,
              const int* __restrict__ ss, const int* __restrict__ sd,
              const int* __restrict__ offs, const float* __restrict__ rel,
              const float* __restrict__ rp, float* __restrict__ att,
              u32* __restrict__ amax)
{
  int r = blockIdx.y;
  int lo = offs[r], hi = offs[r + 1];
  int base = lo + blockIdx.x * 128;
  if (base >= hi) return;
  int tid = threadIdx.x, wv = tid >> 6, lane = tid & 63;
  int f = lane & 31, hp = lane >> 5;
  const float* ra = rel + (long)r * 4096;
  float rA[32], rB[32];
  #pragma unroll
  for (int d = 0; d < 32; d++){
    rA[d] = ra[hp * 1024 + d * 32 + f];
    rB[d] = ra[(hp + 2) * 1024 + d * 32 + f];
  }
  float rpa = rp[r * 4 + hp]     * 0.17677669529663689f;
  float rpb = rp[r * 4 + hp + 2] * 0.17677669529663689f;
  __shared__ __align__(16) float ldsK[4][128];
  int e0 = base + wv * 32;
  for (int i = 0; i < 32; i++){
    int e = e0 + i;
    if (e >= hi) break;
    int s_ = ss[e], dn = sd[e];
    ldsK[wv][lane]      = kv[(long)s_ * HD + lane];
    ldsK[wv][64 + lane] = kv[(long)s_ * HD + 64 + lane];
    float qa = qv[(long)dn * HD + lane];
    float qb = qv[(long)dn * HD + 64 + lane];
    asm volatile("s_waitcnt lgkmcnt(0)" ::: "memory");
    const float4* lka = (const float4*)&ldsK[wv][hp * 32];
    const float4* lkb = (const float4*)&ldsK[wv][64 + hp * 32];
    float a0 = 0, a1 = 0, a2 = 0, a3 = 0, b0 = 0, b1 = 0, b2 = 0, b3 = 0;
    #pragma unroll
    for (int d4 = 0; d4 < 8; d4++){
      float4 x = lka[d4], y = lkb[d4];
      a0 += x.x * rA[d4 * 4 + 0]; a1 += x.y * rA[d4 * 4 + 1];
      a2 += x.z * rA[d4 * 4 + 2]; a3 += x.w * rA[d4 * 4 + 3];
      b0 += y.x * rB[d4 * 4 + 0]; b1 += y.y * rB[d4 * 4 + 1];
      b2 += y.z * rB[d4 * 4 + 2]; b3 += y.w * rB[d4 * 4 + 3];
    }
    float pa = qa * ((a0 + a1) + (a2 + a3));
    float pb = qb * ((b0 + b1) + (b2 + b3));
    #pragma unroll
    for (int m = 1; m < 32; m <<= 1){ pa += __shfl_xor(pa, m); pb += __shfl_xor(pb, m); }
    if (f == 0){
      float aa = pa * rpa, ab = pb * rpb;
      att[(long)e * 4 + hp]     = aa;
      att[(long)e * 4 + hp + 2] = ab;
      atomicMax(&amax[dn * 4 + hp], encf(aa));
      atomicMax(&amax[dn * 4 + hp + 2], encf(ab));
    }
  }
}

// ---------- edge pass B: ea=exp(att-amax); den += ea; res += ea * (rm[r] v_s)
__global__ __launch_bounds__(256)
void edge_msg(const float* __restrict__ vv, const int* __restrict__ ss,
              const int* __restrict__ sd, const int* __restrict__ offs,
              const float* __restrict__ rel, const float* __restrict__ att,
              const u32* __restrict__ amax, float* __restrict__ den,
              float* __restrict__ res)
{
  int r = blockIdx.y;
  int lo = offs[r], hi = offs[r + 1];
  int base = lo + blockIdx.x * 128;
  if (base >= hi) return;
  int tid = threadIdx.x, wv = tid >> 6, lane = tid & 63;
  int f = lane & 31, hp = lane >> 5;
  const float* rm = rel + (long)r * 4096;
  float rA[32], rB[32];
  #pragma unroll
  for (int d = 0; d < 32; d++){
    rA[d] = rm[hp * 1024 + d * 32 + f];
    rB[d] = rm[(hp + 2) * 1024 + d * 32 + f];
  }
  __shared__ __align__(16) float ldsV[4][128];
  int e0 = base + wv * 32;
  for (int i = 0; i < 32; i++){
    int e = e0 + i;
    if (e >= hi) break;
    int s_ = ss[e], dn = sd[e];
    ldsV[wv][lane]      = vv[(long)s_ * HD + lane];
    ldsV[wv][64 + lane] = vv[(long)s_ * HD + 64 + lane];
    float aa = att[(long)e * 4 + hp];
    float ab = att[(long)e * 4 + hp + 2];
    float ma = decf(amax[dn * 4 + hp]);
    float mb = decf(amax[dn * 4 + hp + 2]);
    float ea = __expf(aa - ma), eb = __expf(ab - mb);
    asm volatile("s_waitcnt lgkmcnt(0)" ::: "memory");
    const float4* lva = (const float4*)&ldsV[wv][hp * 32];
    const float4* lvb = (const float4*)&ldsV[wv][64 + hp * 32];
    float a0 = 0, a1 = 0, a2 = 0, a3 = 0, b0 = 0, b1 = 0, b2 = 0, b3 = 0;
    #pragma unroll
    for (int d4 = 0; d4 < 8; d4++){
      float4 x = lva[d4], y = lvb[d4];
      a0 += x.x * rA[d4 * 4 + 0]; a1 += x.y * rA[d4 * 4 + 1];
      a2 += x.z * rA[d4 * 4 + 2]; a3 += x.w * rA[d4 * 4 + 3];
      b0 += y.x * rB[d4 * 4 + 0]; b1 += y.y * rB[d4 * 4 + 1];
      b2 += y.z * rB[d4 * 4 + 2]; b3 += y.w * rB[d4 * 4 + 3];
    }
    float mta = (a0 + a1) + (a2 + a3);
    float mtb = (b0 + b1) + (b2 + b3);
    atomicAdd(&res[(long)dn * HD + lane],      ea * mta);
    atomicAdd(&res[(long)dn * HD + 64 + lane], eb * mtb);
    if (f == 0){
      atomicAdd(&den[dn * 4 + hp],     ea);
      atomicAdd(&den[dn * 4 + hp + 2], eb);
    }
  }
}

// ---------- skip-combine + LayerNorm; writes h (f32) and bf16 mirror
__global__ __launch_bounds__(256)
void combine_ln(const float* __restrict__ trans, float* __restrict__ h,
                u16* __restrict__ hb, const float* __restrict__ skl,
                const float* __restrict__ gm, const float* __restrict__ bt)
{
  int wv = threadIdx.x >> 6, lane = threadIdx.x & 63;
  int node = blockIdx.x * 4 + wv;
  if (node >= NN) return;
  int t = node / NPT;
  float alpha = 1.f / (1.f + __expf(-skl[t]));
  long b0 = (long)node * HD;
  float x0 = trans[b0 + lane]      * alpha + h[b0 + lane]      * (1.f - alpha);
  float x1 = trans[b0 + 64 + lane] * alpha + h[b0 + 64 + lane] * (1.f - alpha);
  float s = x0 + x1;
  #pragma unroll
  for (int m = 1; m < 64; m <<= 1) s += __shfl_xor(s, m);
  float mean = s * (1.f / HD);
  float d0 = x0 - mean, d1 = x1 - mean;
  float vs = d0 * d0 + d1 * d1;
  #pragma unroll
  for (int m = 1; m < 64; m <<= 1) vs += __shfl_xor(vs, m);
  float rstd = rsqrtf(vs * (1.f / HD) + 1e-5f);
  float y0 = d0 * rstd * gm[lane]      + bt[lane];
  float y1 = d1 * rstd * gm[64 + lane] + bt[64 + lane];
  h[b0 + lane] = y0;      h[b0 + 64 + lane] = y1;
  hb[b0 + lane] = f2bf(y0); hb[b0 + 64 + lane] = f2bf(y1);
}

extern "C" void kernel_launch(void* const* d_in, const int* in_sizes, int n_in,
                              void* d_out, int out_size, void* d_ws, size_t ws_size,
                              hipStream_t stream)
{
  const float* nf[4]  = {(const float*)d_in[0], (const float*)d_in[1], (const float*)d_in[2], (const float*)d_in[3]};
  const float* ew1[4] = {(const float*)d_in[4], (const float*)d_in[8],  (const float*)d_in[12], (const float*)d_in[16]};
  const float* eb1[4] = {(const float*)d_in[5], (const float*)d_in[9],  (const float*)d_in[13], (const float*)d_in[17]};
  const float* ew2[4] = {(const float*)d_in[6], (const float*)d_in[10], (const float*)d_in[14], (const float*)d_in[18]};
  const float* eb2[4] = {(const float*)d_in[7], (const float*)d_in[11], (const float*)d_in[15], (const float*)d_in[19]};
  const float* Wk = (const float*)d_in[20]; const float* bk = (const float*)d_in[21];
  const float* Wq = (const float*)d_in[22]; const float* bq = (const float*)d_in[23];
  const float* Wv = (const float*)d_in[24]; const float* bv = (const float*)d_in[25];
  const float* Wa = (const float*)d_in[26]; const float* ba = (const float*)d_in[27];
  const float* rel_att = (const float*)d_in[28];
  const float* rel_msg = (const float*)d_in[29];
  const float* rel_pri = (const float*)d_in[30];
  const float* skp = (const float*)d_in[31];
  const float* gma = (const float*)d_in[32];
  const float* bta = (const float*)d_in[33];
  const int* edge_index = (const int*)d_in[35];
  const int* edge_types = (const int*)d_in[36];
  float* out = (float*)d_out;
  char* ws = (char*)d_ws;

  float* kbuf = (float*)(ws + 0L);
  float* qbuf = (float*)(ws + 51200000L);
  float* vbuf = (float*)(ws + 102400000L);
  float* resb = (float*)(ws + 153600000L);
  float* attb = (float*)(ws + 204800000L);
  u32*   amax = (u32*)  (ws + 214400000L);
  float* denb = (float*)(ws + 216000000L);
  u16*   hbf  = (u16*)  (ws + 217600000L);
  u16*   hid  = (u16*)  (ws + 204800000L);   // aliases att+amax+den (dead while encoders run)
  int*   ss   = (int*)  (ws + 243200000L);
  int*   sd   = (int*)  (ws + 245600000L);
  int*   meta = (int*)  (ws + 248000000L);
  u16*   w1t  = (u16*)  (ws + 248001024L);
  u16*   w2t  = (u16*)  (ws + 248492544L);
  u16*   wkt  = (u16*)  (ws + 248754688L);
  u16*   wqt  = (u16*)  (ws + 249016832L);
  u16*   wvt  = (u16*)  (ws + 249278976L);
  u16*   wat  = (u16*)  (ws + 249541120L);

  int  di[4]  = {512, 256, 128, 64};
  long w1o[4] = {0, 131072, 196608, 229376};

  // weight casts (f32 [K][N] -> bf16 [N][K])
  for (int i = 0; i < 4; i++){
    cast_tr<<<dim3(di[i], 1), 256, 0, stream>>>(ew1[i], w1t + w1o[i], di[i], 256);
    cast_tr<<<dim3(128, 1),  256, 0, stream>>>(ew2[i], w2t + (long)i * 32768, 256, 128);
  }
  cast_tr<<<dim3(64, 8), 256, 0, stream>>>(Wk, wkt, 128, 128);
  cast_tr<<<dim3(64, 8), 256, 0, stream>>>(Wq, wqt, 128, 128);
  cast_tr<<<dim3(64, 8), 256, 0, stream>>>(Wv, wvt, 128, 128);
  cast_tr<<<dim3(64, 8), 256, 0, stream>>>(Wa, wat, 128, 128);

  // relation bucket sort
  hipMemsetAsync(meta, 0, 1024, stream);
  hist_k   <<<2344, 256, 0, stream>>>(edge_types, meta);
  scan_k   <<<1, 64, 0, stream>>>(meta);
  scatter_k<<<2344, 256, 0, stream>>>(edge_index, edge_types, meta, ss, sd);

  // encoders: h = relu(nf@w1+b1)@w2 + b2  -> out (f32) + hbf (bf16)
  for (int i = 0; i < 4; i++){
    gemm_k<1, true,  false, true ><<<dim3(196, 2, 1), 256, 0, stream>>>(
        nf[i], w1t + w1o[i], eb1[i], nullptr, nullptr, hid, NPT, 256, di[i], 0, 0, 0, 0);
    gemm_k<0, false, true,  true ><<<dim3(196, 1, 1), 256, 0, stream>>>(
        hid, w2t + (long)i * 32768, eb2[i], nullptr,
        out + (long)i * NPT * HD, hbf + (long)i * NPT * HD, NPT, 128, 256, 0, 0, 0, 0);
  }

  for (int l = 0; l < 2; l++){
    // typed K,Q,V (batched over types on blockIdx.z)
    gemm_k<0, false, true, false><<<dim3(196, 1, 4), 256, 0, stream>>>(
        hbf, wkt + (long)l * 65536, bk + l * 512, nullptr, kbuf, nullptr,
        NPT, 128, 128, NPT, 16384, 128, NPT);
    gemm_k<0, false, true, false><<<dim3(196, 1, 4), 256, 0, stream>>>(
        hbf, wqt + (long)l * 65536, bq + l * 512, nullptr, qbuf, nullptr,
        NPT, 128, 128, NPT, 16384, 128, NPT);
    gemm_k<0, false, true, false><<<dim3(196, 1, 4), 256, 0, stream>>>(
        hbf, wvt + (long)l * 65536, bv + l * 512, nullptr, vbuf, nullptr,
        NPT, 128, 128, NPT, 16384, 128, NPT);

    hipMemsetAsync(amax, 0, 1600000, stream);
    hipMemsetAsync(denb, 0, 1600000, stream);
    hipMemsetAsync(resb, 0, 51200000, stream);

    edge_att<<<dim3(4688, 8), 256, 0, stream>>>(
        kbuf, qbuf, ss, sd, meta + 16,
        rel_att + (long)l * 32768, rel_pri + l * 32, attb, amax);
    edge_msg<<<dim3(4688, 8), 256, 0, stream>>>(
        vbuf, ss, sd, meta + 16,
        rel_msg + (long)l * 32768, attb, amax, denb, resb);

    // trans = gelu(res/den) @ Wa + ba   (written into kbuf)
    gemm_k<2, false, true, false><<<dim3(196, 1, 4), 256, 0, stream>>>(
        resb, wat + (long)l * 65536, ba + l * 512, denb, kbuf, nullptr,
        NPT, 128, 128, NPT, 16384, 128, NPT);

    combine_ln<<<25000, 256, 0, stream>>>(
        kbuf, out, hbf, skp + l * 4, gma + l * 128, bta + l * 128);
  }
}